// Round 11
// baseline (224.762 us; speedup 1.0000x reference)
//
#include <hip/hip_runtime.h>

#define N_NODES 50000
#define N_EDGES 800000
#define SCAN_TILE 2048     // 256 threads x 8 nodes
#define GEMM1_BLOCKS 782   // one block per tile (neutral vs grid-stride, r10)
#define FILLV_BLOCKS ((N_EDGES / 4 + 255) / 256)  // 782 (4 edges/thread)

// CSR build: per-chunk LDS histograms, u8-packed (NO global atomics — the
// memory-side atomic unit ceilings at ~7.6 ops/cycle device-wide, rounds 0-2).
// Lessons ledger (final):
//  r4/r9: spins co-resident with real work are catastrophic (cache/coherence
//         poison at >=768 pollers); r5: a STANDALONE 25-block spin-scan is
//         safe. r6: in-kernel phases cap at kernel grid width.
//  r7/r10: tail-balancing (dynamic grab, one-block-per-tile) is neutral —
//         the plateau is per-dispatch serialization.
//  r8:    cpack LDS staging in gather kernels is a win (kept).
//  r11:   scan1+scan2 -> one 25-block spin-scan; bbase(int,12.8MB) ->
//         cum8(u8,3.2MB, per-XCD-L2-resident); fill vectorized 4-wide.
#define HB 64                    // histogram chunks/blocks
#define EPB (N_EDGES / HB)       // 12500 edges per chunk (exact)
#define HGROUPS (EPB / 4)        // 3125 int4 groups per chunk
#define HWORDS (N_NODES / 4)     // 12500 uints (4 x u8 counts each) = 50 KB

static_assert(N_NODES < 65536, "col must fit in 16 bits for packed CSR");
static_assert(N_EDGES % (4 * HB) == 0, "chunking must be exact");
static_assert(N_NODES % 8 == 0, "scan uint2 path assumes x8");

typedef __attribute__((ext_vector_type(4))) float f32x4;
typedef __attribute__((ext_vector_type(8))) short bf16x8;

__device__ inline unsigned short f32_to_bf16(float f) {
    unsigned int u = __builtin_bit_cast(unsigned int, f);
    u += 0x7FFF + ((u >> 16) & 1);  // RNE
    return (unsigned short)(u >> 16);
}
__device__ inline float bf16_to_f32(unsigned short h) {
    unsigned int u = ((unsigned int)h) << 16;
    return __builtin_bit_cast(float, u);
}

// ---------------------------------------------------------------------------
// MFMA phase, 256-thread variant (4 waves; wave w: rows w*16..+16, all tiles).
// ---------------------------------------------------------------------------
template <int NOUT>
__device__ __forceinline__ void mfma_phase(const unsigned short* Xs,
                                           const unsigned short* Ws,
                                           unsigned short* __restrict__ Yb,
                                           int block_row, int N) {
    constexpr int KP = 128 + 8;
    constexpr int NT = NOUT / 16;
    const int tid = threadIdx.x;
    const int wave = tid >> 6;
    const int lane = tid & 63;
    const int m = lane & 15;
    const int quad = lane >> 4;
    const int rowbase = wave * 16;

    f32x4 acc[NT];
#pragma unroll
    for (int t = 0; t < NT; ++t) acc[t] = (f32x4){0.f, 0.f, 0.f, 0.f};

#pragma unroll
    for (int kt = 0; kt < 4; ++kt) {
        bf16x8 a = *reinterpret_cast<const bf16x8*>(
            Xs + (rowbase + m) * KP + kt * 32 + quad * 8);
#pragma unroll
        for (int t = 0; t < NT; ++t) {
            bf16x8 b = *reinterpret_cast<const bf16x8*>(
                Ws + (t * 16 + m) * KP + kt * 32 + quad * 8);
            acc[t] = __builtin_amdgcn_mfma_f32_16x16x32_bf16(a, b, acc[t], 0, 0, 0);
        }
    }

#pragma unroll
    for (int t = 0; t < NT; ++t) {
#pragma unroll
        for (int r = 0; r < 4; ++r) {
            int grow = block_row + rowbase + quad * 4 + r;
            if (grow < N)
                Yb[(size_t)grow * NOUT + t * 16 + m] = f32_to_bf16(acc[t][r]);
        }
    }
}

// ---------------------------------------------------------------------------
// Mega-dispatch 1: blocks 0..HB-1 build per-chunk LDS u8 histograms (rank8 +
// bhist, all LDS atomics); blocks HB.. run the layer-1 GEMM (one tile per
// block). NO inter-block spins. Block 0 zeroes the scan's done flag
// (consumed only by the NEXT dispatch — r5-validated pattern).
// ---------------------------------------------------------------------------
__global__ __launch_bounds__(256) void mega1(
    const float* __restrict__ x, const float* __restrict__ W1,
    unsigned short* __restrict__ Yb, int N, int ntiles_g,
    const int* __restrict__ erow, unsigned int* __restrict__ rank8,
    unsigned int* __restrict__ bhist, int* __restrict__ done) {
    constexpr int KP = 128 + 8;
    __shared__ __align__(16) unsigned char smem[52224];
    const int tid = threadIdx.x;

    if (blockIdx.x < HB) {
        const int b = blockIdx.x;
        if (b == 0 && tid == 0) *done = 0;
        unsigned int* h = reinterpret_cast<unsigned int*>(smem);  // HWORDS
        int4* h4 = reinterpret_cast<int4*>(h);
        for (int i = tid; i < HWORDS / 4; i += 256) {
            int4 z = {0, 0, 0, 0};
            h4[i] = z;
        }
        __syncthreads();
        const int4* eg = reinterpret_cast<const int4*>(erow) + (size_t)b * HGROUPS;
        unsigned int* rg = rank8 + (size_t)b * HGROUPS;
        for (int g = tid; g < HGROUPS; g += 256) {
            int4 er = eg[g];
            unsigned int rk;
            int sh;
            unsigned int o;
            sh = (er.x & 3) << 3;
            o = atomicAdd(&h[er.x >> 2], 1u << sh);
            rk = (o >> sh) & 0xFFu;
            sh = (er.y & 3) << 3;
            o = atomicAdd(&h[er.y >> 2], 1u << sh);
            rk |= ((o >> sh) & 0xFFu) << 8;
            sh = (er.z & 3) << 3;
            o = atomicAdd(&h[er.z >> 2], 1u << sh);
            rk |= ((o >> sh) & 0xFFu) << 16;
            sh = (er.w & 3) << 3;
            o = atomicAdd(&h[er.w >> 2], 1u << sh);
            rk |= ((o >> sh) & 0xFFu) << 24;
            rg[g] = rk;
        }
        __syncthreads();
        int4* dst = reinterpret_cast<int4*>(bhist + (size_t)b * HWORDS);
        for (int i = tid; i < HWORDS / 4; i += 256) dst[i] = h4[i];
        return;
    }

    // ---- GEMM part: one tile per block (queued blocks backfill)
    const int gb = blockIdx.x - HB;
    unsigned short* Xs = reinterpret_cast<unsigned short*>(smem);   // 64*KP
    unsigned short* Ws = reinterpret_cast<unsigned short*>(smem) + 64 * KP;

    for (int idx = tid; idx < 128 * 128; idx += 256) {
        int k = idx >> 7, m = idx & 127;
        Ws[m * KP + k] = f32_to_bf16(W1[idx]);
    }

    for (int tile = gb; tile < ntiles_g; tile += GEMM1_BLOCKS) {
        const int block_row = tile * 64;
        for (int idx = tid; idx < 64 * 16; idx += 256) {
            int r = idx >> 4, ch = idx & 15;
            int gr = block_row + r;
            if (gr >= N) gr = N - 1;
            const float4* xp =
                reinterpret_cast<const float4*>(x + (size_t)gr * 128 + ch * 8);
            float4 a = xp[0], b2 = xp[1];
            uint4 o;
            o.x = (unsigned int)f32_to_bf16(a.x) | ((unsigned int)f32_to_bf16(a.y) << 16);
            o.y = (unsigned int)f32_to_bf16(a.z) | ((unsigned int)f32_to_bf16(a.w) << 16);
            o.z = (unsigned int)f32_to_bf16(b2.x) | ((unsigned int)f32_to_bf16(b2.y) << 16);
            o.w = (unsigned int)f32_to_bf16(b2.z) | ((unsigned int)f32_to_bf16(b2.w) << 16);
            *reinterpret_cast<uint4*>(Xs + r * KP + ch * 8) = o;
        }
        __syncthreads();
        mfma_phase<128>(Xs, Ws, Yb, block_row, N);
        __syncthreads();
    }
}

// ---------------------------------------------------------------------------
// Single-dispatch spin-scan (25 blocks, standalone — r5-validated scale):
// deg = sum of 64 u8 chunk hists -> rptr, plus u8 chunk-cumulative cum8
// (cum8[c][node] = sum_{c'<c} hist[c'][node]; <= deg ~ Poisson(16), u8-safe).
// ---------------------------------------------------------------------------
__global__ void scan_fused(const unsigned int* __restrict__ bhist,
                           int* __restrict__ tsum, int* __restrict__ done,
                           int* __restrict__ rptr, unsigned char* __restrict__ cum8,
                           int n, int ntiles) {
    __shared__ int sums[256];
    __shared__ int off_s;
    const int t = threadIdx.x;
    const int b = blockIdx.x;
    const int base = b * SCAN_TILE + t * 8;
    const int widx2 = base >> 3;  // uint2 index within a chunk (6250/chunk)
    const uint2* bh2 = reinterpret_cast<const uint2*>(bhist);
    int v[8], pref[8];
#pragma unroll
    for (int i = 0; i < 8; ++i) v[i] = 0;
    if (base < n) {
        for (int hb = 0; hb < HB; ++hb) {
            uint2 p = bh2[hb * (HWORDS / 2) + widx2];
            v[0] += p.x & 0xFF; v[1] += (p.x >> 8) & 0xFF;
            v[2] += (p.x >> 16) & 0xFF; v[3] += p.x >> 24;
            v[4] += p.y & 0xFF; v[5] += (p.y >> 8) & 0xFF;
            v[6] += (p.y >> 16) & 0xFF; v[7] += p.y >> 24;
        }
    }
    int s = 0;
#pragma unroll
    for (int i = 0; i < 8; ++i) s += v[i];
    sums[t] = s;
    __syncthreads();
    for (int off = 1; off < 256; off <<= 1) {
        int x = (t >= off) ? sums[t - off] : 0;
        __syncthreads();
        sums[t] += x;
        __syncthreads();
    }
    int run = sums[t] - s;
#pragma unroll
    for (int i = 0; i < 8; ++i) {
        pref[i] = run;
        run += v[i];
    }
    if (t == 255) {
        tsum[b] = run;
        __threadfence();
        atomicAdd(done, 1);
    }
    if (t == 0) {
        while (__hip_atomic_load(done, __ATOMIC_ACQUIRE, __HIP_MEMORY_SCOPE_AGENT) <
               ntiles) {
        }
        __threadfence();
        int off = 0;
        for (int i = 0; i < b; ++i) off += tsum[i];
        off_s = off;
        if (b == 0) {
            int tot = 0;
            for (int i = 0; i < ntiles; ++i) tot += tsum[i];
            rptr[n] = tot;
        }
    }
    __syncthreads();
    const int off = off_s;
    if (base < n) {
        int rn[8];
#pragma unroll
        for (int i = 0; i < 8; ++i) rn[i] = pref[i] + off;
        int4 r0 = {rn[0], rn[1], rn[2], rn[3]};
        int4 r1 = {rn[4], rn[5], rn[6], rn[7]};
        *reinterpret_cast<int4*>(rptr + base) = r0;
        *reinterpret_cast<int4*>(rptr + base + 4) = r1;
        unsigned int cm[8];
#pragma unroll
        for (int i = 0; i < 8; ++i) cm[i] = 0;
        for (int hb = 0; hb < HB; ++hb) {
            uint2 w;
            w.x = (cm[0] & 0xFF) | ((cm[1] & 0xFF) << 8) |
                  ((cm[2] & 0xFF) << 16) | ((cm[3] & 0xFF) << 24);
            w.y = (cm[4] & 0xFF) | ((cm[5] & 0xFF) << 8) |
                  ((cm[6] & 0xFF) << 16) | ((cm[7] & 0xFF) << 24);
            *reinterpret_cast<uint2*>(cum8 + (size_t)hb * N_NODES + base) = w;
            uint2 p = bh2[hb * (HWORDS / 2) + widx2];
            cm[0] += p.x & 0xFF; cm[1] += (p.x >> 8) & 0xFF;
            cm[2] += (p.x >> 16) & 0xFF; cm[3] += p.x >> 24;
            cm[4] += p.y & 0xFF; cm[5] += (p.y >> 8) & 0xFF;
            cm[6] += (p.y >> 16) & 0xFF; cm[7] += p.y >> 24;
        }
    }
}

// ---------------------------------------------------------------------------
// Atomic-free CSR fill, vectorized 4 edges/thread:
// slot = rptr[row] + cum8[chunk][row] + rank8-byte. rptr (200KB) and cum8
// (3.2MB) are per-XCD-L2-resident. 782 blocks, full-device MLP.
// ---------------------------------------------------------------------------
__global__ void fill_csr(const int* __restrict__ erow, const int* __restrict__ ecol,
                         const float* __restrict__ eval, const int* __restrict__ rptr,
                         const unsigned char* __restrict__ cum8,
                         const unsigned int* __restrict__ rank8,
                         unsigned int* __restrict__ cpack) {
    int g = blockIdx.x * blockDim.x + threadIdx.x;
    if (g >= N_EDGES / 4) return;
    int4 er = reinterpret_cast<const int4*>(erow)[g];
    int4 ec = reinterpret_cast<const int4*>(ecol)[g];
    float4 ev = reinterpret_cast<const float4*>(eval)[g];
    unsigned int rk = rank8[g];
    const unsigned char* cb = cum8 + (size_t)(g / HGROUPS) * N_NODES;
    int s0 = rptr[er.x] + cb[er.x] + (int)(rk & 0xFF);
    int s1 = rptr[er.y] + cb[er.y] + (int)((rk >> 8) & 0xFF);
    int s2 = rptr[er.z] + cb[er.z] + (int)((rk >> 16) & 0xFF);
    int s3 = rptr[er.w] + cb[er.w] + (int)(rk >> 24);
    cpack[s0] = (unsigned int)(ec.x & 0xFFFF) | ((unsigned int)f32_to_bf16(ev.x) << 16);
    cpack[s1] = (unsigned int)(ec.y & 0xFFFF) | ((unsigned int)f32_to_bf16(ev.y) << 16);
    cpack[s2] = (unsigned int)(ec.z & 0xFFFF) | ((unsigned int)f32_to_bf16(ev.z) << 16);
    cpack[s3] = (unsigned int)(ec.w & 0xFFFF) | ((unsigned int)f32_to_bf16(ev.w) << 16);
}

// ---------------------------------------------------------------------------
// MFMA phase, 512-thread variant (8 waves; wave w: rows (w&3)*16..+16,
// tile-columns (w>>2)*NT/2..+NT/2).
// ---------------------------------------------------------------------------
template <int NOUT>
__device__ __forceinline__ void mfma_phase512(const unsigned short* Xs,
                                              const unsigned short* Ws,
                                              unsigned short* __restrict__ Yb,
                                              int block_row, int N) {
    constexpr int KP = 128 + 8;
    constexpr int NT = NOUT / 16;
    constexpr int NTH = NT / 2;
    const int tid = threadIdx.x;
    const int wave = tid >> 6;
    const int lane = tid & 63;
    const int m = lane & 15;
    const int quad = lane >> 4;
    const int rowbase = (wave & 3) * 16;
    const int tbase = (wave >> 2) * NTH;

    f32x4 acc[NTH];
#pragma unroll
    for (int t = 0; t < NTH; ++t) acc[t] = (f32x4){0.f, 0.f, 0.f, 0.f};

#pragma unroll
    for (int kt = 0; kt < 4; ++kt) {
        bf16x8 a = *reinterpret_cast<const bf16x8*>(
            Xs + (rowbase + m) * KP + kt * 32 + quad * 8);
#pragma unroll
        for (int t = 0; t < NTH; ++t) {
            bf16x8 b = *reinterpret_cast<const bf16x8*>(
                Ws + ((tbase + t) * 16 + m) * KP + kt * 32 + quad * 8);
            acc[t] = __builtin_amdgcn_mfma_f32_16x16x32_bf16(a, b, acc[t], 0, 0, 0);
        }
    }

#pragma unroll
    for (int t = 0; t < NTH; ++t) {
#pragma unroll
        for (int r = 0; r < 4; ++r) {
            int grow = block_row + rowbase + quad * 4 + r;
            if (grow < N)
                Yb[(size_t)grow * NOUT + (tbase + t) * 16 + m] = f32_to_bf16(acc[t][r]);
        }
    }
}

// ---------------------------------------------------------------------------
// Fused aggregation + GEMM (layers 2,3), 512-thread blocks, 2 blocks/CU,
// one tile per block. Tile's contiguous cpack slice staged in LDS (r8 win;
// cap 2048 = +32 sigma). Phase A: 32 groups x 16 lanes gather-aggregate 64
// rows (+bias, ReLU, pack bf16 into Xs). Phase B: mfma_phase512.
// ---------------------------------------------------------------------------
template <int NOUT>
__global__ __launch_bounds__(512, 4) void gemm_fused_agg(
    const unsigned short* __restrict__ S,
    const int* __restrict__ rptr, const unsigned int* __restrict__ cpack,
    const float* __restrict__ bias,
    const float* __restrict__ W,
    unsigned short* __restrict__ Yb,
    int N, int ntiles) {
    constexpr int KP = 128 + 8;
    __shared__ unsigned short Xs[64 * KP];
    __shared__ unsigned short Ws[NOUT * KP];
    __shared__ unsigned int cp_s[2048];
    const int tid = threadIdx.x;
    const int group = tid >> 4;   // 0..31
    const int f8 = tid & 15;

    for (int idx = tid; idx < 128 * NOUT; idx += 512) {
        int k = idx / NOUT, m = idx % NOUT;
        Ws[m * KP + k] = f32_to_bf16(W[idx]);
    }

    float bv[8];
#pragma unroll
    for (int i = 0; i < 8; ++i) bv[i] = bias[f8 * 8 + i];

    for (int tile = blockIdx.x; tile < ntiles; tile += gridDim.x) {
        const int block_row = tile * 64;
        const int rend = (block_row + 64 < N) ? block_row + 64 : N;
        const int ebeg = rptr[block_row];
        const int ecount = rptr[rend] - ebeg;
        __syncthreads();  // W-staging (first iter) / prev Phase B done
        for (int i = tid; i < ecount; i += 512) cp_s[i] = cpack[ebeg + i];
        __syncthreads();
#pragma unroll
        for (int r4 = 0; r4 < 2; ++r4) {
            const int row = r4 * 32 + group;
            const int node = block_row + row;
            float acc[8];
#pragma unroll
            for (int i = 0; i < 8; ++i) acc[i] = bv[i];
            if (node < N) {
                const int beg = rptr[node] - ebeg;
                const int end = rptr[node + 1] - ebeg;
                int j = beg;
                for (; j + 8 <= end; j += 8) {
                    unsigned int p[8];
                    uint4 s[8];
#pragma unroll
                    for (int u = 0; u < 8; ++u) p[u] = cp_s[j + u];
#pragma unroll
                    for (int u = 0; u < 8; ++u)
                        s[u] = *reinterpret_cast<const uint4*>(
                            S + (size_t)(p[u] & 0xFFFF) * 128 + f8 * 8);
#pragma unroll
                    for (int u = 0; u < 8; ++u) {
                        const float v = bf16_to_f32((unsigned short)(p[u] >> 16));
                        const unsigned short* sp =
                            reinterpret_cast<const unsigned short*>(&s[u]);
#pragma unroll
                        for (int i = 0; i < 8; ++i)
                            acc[i] = fmaf(v, bf16_to_f32(sp[i]), acc[i]);
                    }
                }
                if (j + 4 <= end) {
                    unsigned int p[4];
                    uint4 s[4];
#pragma unroll
                    for (int u = 0; u < 4; ++u) p[u] = cp_s[j + u];
#pragma unroll
                    for (int u = 0; u < 4; ++u)
                        s[u] = *reinterpret_cast<const uint4*>(
                            S + (size_t)(p[u] & 0xFFFF) * 128 + f8 * 8);
#pragma unroll
                    for (int u = 0; u < 4; ++u) {
                        const float v = bf16_to_f32((unsigned short)(p[u] >> 16));
                        const unsigned short* sp =
                            reinterpret_cast<const unsigned short*>(&s[u]);
#pragma unroll
                        for (int i = 0; i < 8; ++i)
                            acc[i] = fmaf(v, bf16_to_f32(sp[i]), acc[i]);
                    }
                    j += 4;
                }
                if (j + 2 <= end) {
                    unsigned int p[2];
                    uint4 s[2];
#pragma unroll
                    for (int u = 0; u < 2; ++u) p[u] = cp_s[j + u];
#pragma unroll
                    for (int u = 0; u < 2; ++u)
                        s[u] = *reinterpret_cast<const uint4*>(
                            S + (size_t)(p[u] & 0xFFFF) * 128 + f8 * 8);
#pragma unroll
                    for (int u = 0; u < 2; ++u) {
                        const float v = bf16_to_f32((unsigned short)(p[u] >> 16));
                        const unsigned short* sp =
                            reinterpret_cast<const unsigned short*>(&s[u]);
#pragma unroll
                        for (int i = 0; i < 8; ++i)
                            acc[i] = fmaf(v, bf16_to_f32(sp[i]), acc[i]);
                    }
                    j += 2;
                }
                if (j < end) {
                    unsigned int p = cp_s[j];
                    uint4 s = *reinterpret_cast<const uint4*>(
                        S + (size_t)(p & 0xFFFF) * 128 + f8 * 8);
                    const float v = bf16_to_f32((unsigned short)(p >> 16));
                    const unsigned short* sp =
                        reinterpret_cast<const unsigned short*>(&s);
#pragma unroll
                    for (int i = 0; i < 8; ++i)
                        acc[i] = fmaf(v, bf16_to_f32(sp[i]), acc[i]);
                }
            }
            uint4 o;
            o.x = (unsigned int)f32_to_bf16(fmaxf(acc[0], 0.f)) |
                  ((unsigned int)f32_to_bf16(fmaxf(acc[1], 0.f)) << 16);
            o.y = (unsigned int)f32_to_bf16(fmaxf(acc[2], 0.f)) |
                  ((unsigned int)f32_to_bf16(fmaxf(acc[3], 0.f)) << 16);
            o.z = (unsigned int)f32_to_bf16(fmaxf(acc[4], 0.f)) |
                  ((unsigned int)f32_to_bf16(fmaxf(acc[5], 0.f)) << 16);
            o.w = (unsigned int)f32_to_bf16(fmaxf(acc[6], 0.f)) |
                  ((unsigned int)f32_to_bf16(fmaxf(acc[7], 0.f)) << 16);
            *reinterpret_cast<uint4*>(Xs + row * KP + f8 * 8) = o;
        }
        __syncthreads();
        mfma_phase512<NOUT>(Xs, Ws, Yb, block_row, N);
    }
}

// ---------------------------------------------------------------------------
// Final aggregation: bf16 source [N,64], + bias, no activation, fp32 out.
// 8 lanes/node; block's 32-node cpack slice staged in LDS (cap 1536 = +45s).
// ---------------------------------------------------------------------------
__global__ void aggregate_bf16_64(const unsigned short* __restrict__ S,
                                  const int* __restrict__ rptr,
                                  const unsigned int* __restrict__ cpack,
                                  const float* __restrict__ bias,
                                  float* __restrict__ out, int N) {
    __shared__ unsigned int cp_s[1536];
    const int t = threadIdx.x;
    const int nfirst = blockIdx.x * 32;
    const int node = nfirst + (t >> 3);
    const int f8 = t & 7;
    const int nlast1 = (nfirst + 32 < N) ? nfirst + 32 : N;
    int ebeg = 0, ecount = 0;
    if (nfirst < N) {
        ebeg = rptr[nfirst];
        ecount = rptr[nlast1] - ebeg;
    }
    for (int i = t; i < ecount; i += 256) cp_s[i] = cpack[ebeg + i];
    __syncthreads();
    if (node >= N) return;  // after the only barrier — safe
    int j = rptr[node] - ebeg;
    const int end = rptr[node + 1] - ebeg;
    float acc[8];
#pragma unroll
    for (int i = 0; i < 8; ++i) acc[i] = bias[f8 * 8 + i];
    for (; j + 8 <= end; j += 8) {
        unsigned int p[8];
        uint4 s[8];
#pragma unroll
        for (int u = 0; u < 8; ++u) p[u] = cp_s[j + u];
#pragma unroll
        for (int u = 0; u < 8; ++u)
            s[u] = *reinterpret_cast<const uint4*>(S + (size_t)(p[u] & 0xFFFF) * 64 + f8 * 8);
#pragma unroll
        for (int u = 0; u < 8; ++u) {
            const float v = bf16_to_f32((unsigned short)(p[u] >> 16));
            const unsigned short* sp = reinterpret_cast<const unsigned short*>(&s[u]);
#pragma unroll
            for (int i = 0; i < 8; ++i) acc[i] = fmaf(v, bf16_to_f32(sp[i]), acc[i]);
        }
    }
    if (j + 4 <= end) {
        unsigned int p[4];
        uint4 s[4];
#pragma unroll
        for (int u = 0; u < 4; ++u) p[u] = cp_s[j + u];
#pragma unroll
        for (int u = 0; u < 4; ++u)
            s[u] = *reinterpret_cast<const uint4*>(S + (size_t)(p[u] & 0xFFFF) * 64 + f8 * 8);
#pragma unroll
        for (int u = 0; u < 4; ++u) {
            const float v = bf16_to_f32((unsigned short)(p[u] >> 16));
            const unsigned short* sp = reinterpret_cast<const unsigned short*>(&s[u]);
#pragma unroll
            for (int i = 0; i < 8; ++i) acc[i] = fmaf(v, bf16_to_f32(sp[i]), acc[i]);
        }
        j += 4;
    }
    if (j + 2 <= end) {
        unsigned int p[2];
        uint4 s[2];
#pragma unroll
        for (int u = 0; u < 2; ++u) p[u] = cp_s[j + u];
#pragma unroll
        for (int u = 0; u < 2; ++u)
            s[u] = *reinterpret_cast<const uint4*>(S + (size_t)(p[u] & 0xFFFF) * 64 + f8 * 8);
#pragma unroll
        for (int u = 0; u < 2; ++u) {
            const float v = bf16_to_f32((unsigned short)(p[u] >> 16));
            const unsigned short* sp = reinterpret_cast<const unsigned short*>(&s[u]);
#pragma unroll
            for (int i = 0; i < 8; ++i) acc[i] = fmaf(v, bf16_to_f32(sp[i]), acc[i]);
        }
        j += 2;
    }
    if (j < end) {
        unsigned int p = cp_s[j];
        uint4 s = *reinterpret_cast<const uint4*>(S + (size_t)(p & 0xFFFF) * 64 + f8 * 8);
        const float v = bf16_to_f32((unsigned short)(p >> 16));
        const unsigned short* sp = reinterpret_cast<const unsigned short*>(&s);
#pragma unroll
        for (int i = 0; i < 8; ++i) acc[i] = fmaf(v, bf16_to_f32(sp[i]), acc[i]);
    }
    float4 o0 = {acc[0], acc[1], acc[2], acc[3]};
    float4 o1 = {acc[4], acc[5], acc[6], acc[7]};
    float* op = out + (size_t)node * 64 + f8 * 8;
    *reinterpret_cast<float4*>(op) = o0;
    *reinterpret_cast<float4*>(op + 4) = o1;
}

extern "C" void kernel_launch(void* const* d_in, const int* in_sizes, int n_in,
                              void* d_out, int out_size, void* d_ws, size_t ws_size,
                              hipStream_t stream) {
    const float* x    = (const float*)d_in[0];
    const int*   erow = (const int*)d_in[1];
    const int*   ecol = (const int*)d_in[2];
    const float* eval = (const float*)d_in[3];
    const float* W1   = (const float*)d_in[4];
    const float* b1   = (const float*)d_in[5];
    const float* W2   = (const float*)d_in[6];
    const float* b2   = (const float*)d_in[7];
    const float* W3   = (const float*)d_in[8];
    const float* b3   = (const float*)d_in[9];
    float* out = (float*)d_out;

    const size_t nf = (size_t)N_NODES * 128;
    unsigned short* SA    = (unsigned short*)d_ws;           // support A (A1, A3)
    unsigned short* SB    = SA + nf;                         // support B (A2)
    unsigned int*   rank8 = (unsigned int*)(SB + nf);        // N_EDGES/4 uints
    unsigned int*   bhist = rank8 + N_EDGES / 4;             // HB * HWORDS uints
    unsigned char*  cum8  = (unsigned char*)(bhist + (size_t)HB * HWORDS);  // HB*N u8
    int*   rptr   = (int*)(cum8 + (size_t)HB * N_NODES);     // N_NODES + 1
    unsigned int* cpack = (unsigned int*)(rptr + N_NODES + 1);  // N_EDGES
    int*   tsum   = (int*)(cpack + N_EDGES);                 // 32 (scan tiles)
    int*   done   = tsum + 64;                               // own cache line

    const int blk = 256;
    const int ntiles_g = (N_NODES + 63) / 64;  // 782
    const int agg_grid = (int)(((long long)N_NODES * 8 + blk - 1) / blk);
    const int ntiles = (N_NODES + SCAN_TILE - 1) / SCAN_TILE;  // 25

    // ---- 1. mega1: LDS chunk-histograms + rank (blocks 0..63) overlapped
    //         with layer-1 GEMM, one tile per block (78 queued backfill)
    mega1<<<HB + GEMM1_BLOCKS, blk, 0, stream>>>(
        x, W1, SA, N_NODES, ntiles_g, erow, rank8, bhist, done);

    // ---- 2. single-dispatch spin-scan -> rptr + cum8 (25 blocks, standalone)
    scan_fused<<<ntiles, blk, 0, stream>>>(bhist, tsum, done, rptr, cum8,
                                           N_NODES, ntiles);

    // ---- 3. atomic-free vectorized CSR fill (4 edges/thread)
    fill_csr<<<FILLV_BLOCKS, blk, 0, stream>>>(erow, ecol, eval, rptr, cum8,
                                               rank8, cpack);

    // ---- 4. Layer 2: fused agg(A1)+ReLU+b1 -> GEMM W2 -> A2 (one tile/block)
    gemm_fused_agg<128><<<ntiles_g, 512, 0, stream>>>(
        SA, rptr, cpack, b1, W2, SB, N_NODES, ntiles_g);

    // ---- 5. Layer 3: fused agg(A2)+ReLU+b2 -> GEMM W3 -> A3 (one tile/block)
    gemm_fused_agg<64><<<ntiles_g, 512, 0, stream>>>(
        SB, rptr, cpack, b2, W3, SA, N_NODES, ntiles_g);

    // ---- 6. Final aggregation: A3 + b3 -> out (fp32)
    aggregate_bf16_64<<<agg_grid, blk, 0, stream>>>(SA, rptr, cpack, b3, out, N_NODES);
}

// Round 12
// 224.234 us; speedup vs baseline: 1.0024x; 1.0024x over previous
//
#include <hip/hip_runtime.h>

#define N_NODES 50000
#define N_EDGES 800000
#define GEMM1_BLOCKS 704   // layer-1 gemm blocks; 64 CSR + 704 = 768 = 3/CU exact
#define FUSED_BLOCKS 512   // fused agg+gemm: 512-thr blocks, 2/CU (empirical best)
#define FILL_BLOCKS ((N_EDGES + 255) / 256)  // 3125
#define SCAN_BLOCKS ((N_NODES + 255) / 256)  // 196 (wide, spin-free scan)

// CSR build: per-chunk LDS histograms, u8-packed (NO global atomics — the
// memory-side atomic unit ceilings at ~7.6 ops/cycle device-wide, rounds 0-2).
// Lessons ledger (final):
//  r4/r9:  spins co-resident with real work are catastrophic; r6: in-kernel
//          phases cap at kernel grid width => CSR chain stays as separate
//          dispatches; boundaries ARE the cheap barrier.
//  r7/r10: tail-balancing (dynamic grab, one-block-per-tile) is neutral.
//  r8:     cpack LDS staging in gather kernels is a win (kept); best = 220us.
//  r11:    25-spinner scan + cum8 + vectorized fill: slightly negative ->
//          reverted to r8 chain.
//  r12:    dual-row interleaved gather in fused kernels (2 independent
//          load->FMA chains per 16-lane group; 16 outstanding gathers).
#define HB 64                    // histogram chunks/blocks
#define EPB (N_EDGES / HB)       // 12500 edges per chunk (exact)
#define HGROUPS (EPB / 4)        // 3125 int4 groups per chunk
#define HWORDS (N_NODES / 4)     // 12500 uints (4 x u8 counts each) = 50 KB

static_assert(N_NODES < 65536, "col must fit in 16 bits for packed CSR");
static_assert(N_EDGES % (4 * HB) == 0, "chunking must be exact");

typedef __attribute__((ext_vector_type(4))) float f32x4;
typedef __attribute__((ext_vector_type(8))) short bf16x8;

__device__ inline unsigned short f32_to_bf16(float f) {
    unsigned int u = __builtin_bit_cast(unsigned int, f);
    u += 0x7FFF + ((u >> 16) & 1);  // RNE
    return (unsigned short)(u >> 16);
}
__device__ inline float bf16_to_f32(unsigned short h) {
    unsigned int u = ((unsigned int)h) << 16;
    return __builtin_bit_cast(float, u);
}

// ---------------------------------------------------------------------------
// MFMA phase, 256-thread variant (4 waves; wave w: rows w*16..+16, all tiles).
// ---------------------------------------------------------------------------
template <int NOUT>
__device__ __forceinline__ void mfma_phase(const unsigned short* Xs,
                                           const unsigned short* Ws,
                                           unsigned short* __restrict__ Yb,
                                           int block_row, int N) {
    constexpr int KP = 128 + 8;
    constexpr int NT = NOUT / 16;
    const int tid = threadIdx.x;
    const int wave = tid >> 6;
    const int lane = tid & 63;
    const int m = lane & 15;
    const int quad = lane >> 4;
    const int rowbase = wave * 16;

    f32x4 acc[NT];
#pragma unroll
    for (int t = 0; t < NT; ++t) acc[t] = (f32x4){0.f, 0.f, 0.f, 0.f};

#pragma unroll
    for (int kt = 0; kt < 4; ++kt) {
        bf16x8 a = *reinterpret_cast<const bf16x8*>(
            Xs + (rowbase + m) * KP + kt * 32 + quad * 8);
#pragma unroll
        for (int t = 0; t < NT; ++t) {
            bf16x8 b = *reinterpret_cast<const bf16x8*>(
                Ws + (t * 16 + m) * KP + kt * 32 + quad * 8);
            acc[t] = __builtin_amdgcn_mfma_f32_16x16x32_bf16(a, b, acc[t], 0, 0, 0);
        }
    }

#pragma unroll
    for (int t = 0; t < NT; ++t) {
#pragma unroll
        for (int r = 0; r < 4; ++r) {
            int grow = block_row + rowbase + quad * 4 + r;
            if (grow < N)
                Yb[(size_t)grow * NOUT + t * 16 + m] = f32_to_bf16(acc[t][r]);
        }
    }
}

// ---------------------------------------------------------------------------
// Mega-dispatch 1: blocks 0..HB-1 build per-chunk LDS u8 histograms (rank8 +
// bhist, all LDS atomics); blocks HB.. run the layer-1 GEMM (grid-stride).
// ---------------------------------------------------------------------------
__global__ __launch_bounds__(256) void mega1(
    const float* __restrict__ x, const float* __restrict__ W1,
    unsigned short* __restrict__ Yb, int N, int ntiles_g,
    const int* __restrict__ erow, unsigned int* __restrict__ rank8,
    unsigned int* __restrict__ bhist) {
    constexpr int KP = 128 + 8;
    __shared__ __align__(16) unsigned char smem[52224];
    const int tid = threadIdx.x;

    if (blockIdx.x < HB) {
        const int b = blockIdx.x;
        unsigned int* h = reinterpret_cast<unsigned int*>(smem);  // HWORDS
        int4* h4 = reinterpret_cast<int4*>(h);
        for (int i = tid; i < HWORDS / 4; i += 256) {
            int4 z = {0, 0, 0, 0};
            h4[i] = z;
        }
        __syncthreads();
        const int4* eg = reinterpret_cast<const int4*>(erow) + (size_t)b * HGROUPS;
        unsigned int* rg = rank8 + (size_t)b * HGROUPS;
        for (int g = tid; g < HGROUPS; g += 256) {
            int4 er = eg[g];
            unsigned int rk;
            int sh;
            unsigned int o;
            sh = (er.x & 3) << 3;
            o = atomicAdd(&h[er.x >> 2], 1u << sh);
            rk = (o >> sh) & 0xFFu;
            sh = (er.y & 3) << 3;
            o = atomicAdd(&h[er.y >> 2], 1u << sh);
            rk |= ((o >> sh) & 0xFFu) << 8;
            sh = (er.z & 3) << 3;
            o = atomicAdd(&h[er.z >> 2], 1u << sh);
            rk |= ((o >> sh) & 0xFFu) << 16;
            sh = (er.w & 3) << 3;
            o = atomicAdd(&h[er.w >> 2], 1u << sh);
            rk |= ((o >> sh) & 0xFFu) << 24;
            rg[g] = rk;
        }
        __syncthreads();
        int4* dst = reinterpret_cast<int4*>(bhist + (size_t)b * HWORDS);
        for (int i = tid; i < HWORDS / 4; i += 256) dst[i] = h4[i];
        return;
    }

    // ---- GEMM part (grid-stride, r8 structure)
    const int gb = blockIdx.x - HB;
    unsigned short* Xs = reinterpret_cast<unsigned short*>(smem);   // 64*KP
    unsigned short* Ws = reinterpret_cast<unsigned short*>(smem) + 64 * KP;

    for (int idx = tid; idx < 128 * 128; idx += 256) {
        int k = idx >> 7, m = idx & 127;
        Ws[m * KP + k] = f32_to_bf16(W1[idx]);
    }

    for (int tile = gb; tile < ntiles_g; tile += GEMM1_BLOCKS) {
        const int block_row = tile * 64;
        for (int idx = tid; idx < 64 * 16; idx += 256) {
            int r = idx >> 4, ch = idx & 15;
            int gr = block_row + r;
            if (gr >= N) gr = N - 1;
            const float4* xp =
                reinterpret_cast<const float4*>(x + (size_t)gr * 128 + ch * 8);
            float4 a = xp[0], b2 = xp[1];
            uint4 o;
            o.x = (unsigned int)f32_to_bf16(a.x) | ((unsigned int)f32_to_bf16(a.y) << 16);
            o.y = (unsigned int)f32_to_bf16(a.z) | ((unsigned int)f32_to_bf16(a.w) << 16);
            o.z = (unsigned int)f32_to_bf16(b2.x) | ((unsigned int)f32_to_bf16(b2.y) << 16);
            o.w = (unsigned int)f32_to_bf16(b2.z) | ((unsigned int)f32_to_bf16(b2.w) << 16);
            *reinterpret_cast<uint4*>(Xs + r * KP + ch * 8) = o;
        }
        __syncthreads();
        mfma_phase<128>(Xs, Ws, Yb, block_row, N);
        __syncthreads();
    }
}

// ---------------------------------------------------------------------------
// Wide spin-free scan, part 1 (196 blocks, 256 thr, one node/thread).
// ---------------------------------------------------------------------------
__global__ void scan1(const unsigned int* __restrict__ bhist,
                      int* __restrict__ pref, int* __restrict__ btot, int n) {
    __shared__ int sums[256];
    const int t = threadIdx.x;
    const int b = blockIdx.x;
    const int node = b * 256 + t;
    const unsigned char* bh8 = reinterpret_cast<const unsigned char*>(bhist);
    int deg = 0;
    if (node < n) {
        for (int c = 0; c < HB; ++c) deg += bh8[(size_t)c * N_NODES + node];
    }
    sums[t] = deg;
    __syncthreads();
    for (int off = 1; off < 256; off <<= 1) {
        int x = (t >= off) ? sums[t - off] : 0;
        __syncthreads();
        sums[t] += x;
        __syncthreads();
    }
    if (node < n) pref[node] = sums[t] - deg;
    if (t == 255) btot[b] = sums[255];
}

// ---------------------------------------------------------------------------
// Wide spin-free scan, part 2 (196 blocks): rptr + per-(chunk,node) bbase.
// ---------------------------------------------------------------------------
__global__ void scan2(const unsigned int* __restrict__ bhist,
                      const int* __restrict__ pref, const int* __restrict__ btot,
                      int* __restrict__ rptr, int* __restrict__ bbase,
                      int n, int nblocks) {
    __shared__ int off_s, tot_s;
    const int t = threadIdx.x;
    const int b = blockIdx.x;
    const int node = b * 256 + t;
    if (t == 0) {
        int off = 0, tot = 0;
        for (int i = 0; i < nblocks; ++i) {
            int v = btot[i];
            if (i < b) off += v;
            tot += v;
        }
        off_s = off;
        tot_s = tot;
    }
    __syncthreads();
    if (node < n) {
        int run = off_s + pref[node];
        rptr[node] = run;
        const unsigned char* bh8 = reinterpret_cast<const unsigned char*>(bhist);
        for (int c = 0; c < HB; ++c) {
            bbase[(size_t)c * N_NODES + node] = run;
            run += bh8[(size_t)c * N_NODES + node];
        }
    }
    if (b == 0 && t == 0) rptr[n] = tot_s;
}

// ---------------------------------------------------------------------------
// Atomic-free CSR fill: slot = bbase[chunk(e)][row] + rank8[e]; 4B store.
// ---------------------------------------------------------------------------
__global__ void fill_csr(const int* __restrict__ erow, const int* __restrict__ ecol,
                         const float* __restrict__ eval, const int* __restrict__ bbase,
                         const unsigned int* __restrict__ rank8,
                         unsigned int* __restrict__ cpack) {
    int e = blockIdx.x * blockDim.x + threadIdx.x;
    if (e >= N_EDGES) return;
    const unsigned char* r8 = reinterpret_cast<const unsigned char*>(rank8);
    int slot = bbase[(size_t)(e / EPB) * N_NODES + erow[e]] + r8[e];
    unsigned int p = (unsigned int)(ecol[e] & 0xFFFF) |
                     ((unsigned int)f32_to_bf16(eval[e]) << 16);
    cpack[slot] = p;
}

// ---------------------------------------------------------------------------
// MFMA phase, 512-thread variant (8 waves; wave w: rows (w&3)*16..+16,
// tile-columns (w>>2)*NT/2..+NT/2).
// ---------------------------------------------------------------------------
template <int NOUT>
__device__ __forceinline__ void mfma_phase512(const unsigned short* Xs,
                                              const unsigned short* Ws,
                                              unsigned short* __restrict__ Yb,
                                              int block_row, int N) {
    constexpr int KP = 128 + 8;
    constexpr int NT = NOUT / 16;
    constexpr int NTH = NT / 2;
    const int tid = threadIdx.x;
    const int wave = tid >> 6;
    const int lane = tid & 63;
    const int m = lane & 15;
    const int quad = lane >> 4;
    const int rowbase = (wave & 3) * 16;
    const int tbase = (wave >> 2) * NTH;

    f32x4 acc[NTH];
#pragma unroll
    for (int t = 0; t < NTH; ++t) acc[t] = (f32x4){0.f, 0.f, 0.f, 0.f};

#pragma unroll
    for (int kt = 0; kt < 4; ++kt) {
        bf16x8 a = *reinterpret_cast<const bf16x8*>(
            Xs + (rowbase + m) * KP + kt * 32 + quad * 8);
#pragma unroll
        for (int t = 0; t < NTH; ++t) {
            bf16x8 b = *reinterpret_cast<const bf16x8*>(
                Ws + ((tbase + t) * 16 + m) * KP + kt * 32 + quad * 8);
            acc[t] = __builtin_amdgcn_mfma_f32_16x16x32_bf16(a, b, acc[t], 0, 0, 0);
        }
    }

#pragma unroll
    for (int t = 0; t < NTH; ++t) {
#pragma unroll
        for (int r = 0; r < 4; ++r) {
            int grow = block_row + rowbase + quad * 4 + r;
            if (grow < N)
                Yb[(size_t)grow * NOUT + (tbase + t) * 16 + m] = f32_to_bf16(acc[t][r]);
        }
    }
}

// ---------------------------------------------------------------------------
// Tiered 8/4/2/1 drain for one row's remaining edges (S stride = 128).
// ---------------------------------------------------------------------------
__device__ __forceinline__ void drain_row(const unsigned short* __restrict__ S,
                                          const unsigned int* cp_s, int j, int end,
                                          int f8, float* acc) {
    for (; j + 8 <= end; j += 8) {
        unsigned int p[8];
        uint4 s[8];
#pragma unroll
        for (int u = 0; u < 8; ++u) p[u] = cp_s[j + u];
#pragma unroll
        for (int u = 0; u < 8; ++u)
            s[u] = *reinterpret_cast<const uint4*>(
                S + (size_t)(p[u] & 0xFFFF) * 128 + f8 * 8);
#pragma unroll
        for (int u = 0; u < 8; ++u) {
            const float v = bf16_to_f32((unsigned short)(p[u] >> 16));
            const unsigned short* sp = reinterpret_cast<const unsigned short*>(&s[u]);
#pragma unroll
            for (int i = 0; i < 8; ++i) acc[i] = fmaf(v, bf16_to_f32(sp[i]), acc[i]);
        }
    }
    if (j + 4 <= end) {
        unsigned int p[4];
        uint4 s[4];
#pragma unroll
        for (int u = 0; u < 4; ++u) p[u] = cp_s[j + u];
#pragma unroll
        for (int u = 0; u < 4; ++u)
            s[u] = *reinterpret_cast<const uint4*>(
                S + (size_t)(p[u] & 0xFFFF) * 128 + f8 * 8);
#pragma unroll
        for (int u = 0; u < 4; ++u) {
            const float v = bf16_to_f32((unsigned short)(p[u] >> 16));
            const unsigned short* sp = reinterpret_cast<const unsigned short*>(&s[u]);
#pragma unroll
            for (int i = 0; i < 8; ++i) acc[i] = fmaf(v, bf16_to_f32(sp[i]), acc[i]);
        }
        j += 4;
    }
    if (j + 2 <= end) {
        unsigned int p[2];
        uint4 s[2];
#pragma unroll
        for (int u = 0; u < 2; ++u) p[u] = cp_s[j + u];
#pragma unroll
        for (int u = 0; u < 2; ++u)
            s[u] = *reinterpret_cast<const uint4*>(
                S + (size_t)(p[u] & 0xFFFF) * 128 + f8 * 8);
#pragma unroll
        for (int u = 0; u < 2; ++u) {
            const float v = bf16_to_f32((unsigned short)(p[u] >> 16));
            const unsigned short* sp = reinterpret_cast<const unsigned short*>(&s[u]);
#pragma unroll
            for (int i = 0; i < 8; ++i) acc[i] = fmaf(v, bf16_to_f32(sp[i]), acc[i]);
        }
        j += 2;
    }
    if (j < end) {
        unsigned int p = cp_s[j];
        uint4 s = *reinterpret_cast<const uint4*>(
            S + (size_t)(p & 0xFFFF) * 128 + f8 * 8);
        const float v = bf16_to_f32((unsigned short)(p >> 16));
        const unsigned short* sp = reinterpret_cast<const unsigned short*>(&s);
#pragma unroll
        for (int i = 0; i < 8; ++i) acc[i] = fmaf(v, bf16_to_f32(sp[i]), acc[i]);
    }
}

// ---------------------------------------------------------------------------
// Fused aggregation + GEMM (layers 2,3), 512-thread blocks, 2 blocks/CU.
// Tile's contiguous cpack slice staged in LDS (r8 win; cap 2048 = +32 sigma).
// Phase A (r12): each 16-lane group processes its TWO rows (g, g+32)
// INTERLEAVED — two independent load->FMA chains, 16 outstanding gathers,
// halving exposed L3 latency per edge. Tails drain via tiered ladder.
// Phase B: mfma_phase512.
// ---------------------------------------------------------------------------
template <int NOUT>
__global__ __launch_bounds__(512, 4) void gemm_fused_agg(
    const unsigned short* __restrict__ S,
    const int* __restrict__ rptr, const unsigned int* __restrict__ cpack,
    const float* __restrict__ bias,
    const float* __restrict__ W,
    unsigned short* __restrict__ Yb,
    int N, int ntiles) {
    constexpr int KP = 128 + 8;
    __shared__ unsigned short Xs[64 * KP];
    __shared__ unsigned short Ws[NOUT * KP];
    __shared__ unsigned int cp_s[2048];
    const int tid = threadIdx.x;
    const int group = tid >> 4;   // 0..31
    const int f8 = tid & 15;

    for (int idx = tid; idx < 128 * NOUT; idx += 512) {
        int k = idx / NOUT, m = idx % NOUT;
        Ws[m * KP + k] = f32_to_bf16(W[idx]);
    }

    float bv[8];
#pragma unroll
    for (int i = 0; i < 8; ++i) bv[i] = bias[f8 * 8 + i];

    for (int tile = blockIdx.x; tile < ntiles; tile += gridDim.x) {
        const int block_row = tile * 64;
        const int rend = (block_row + 64 < N) ? block_row + 64 : N;
        const int ebeg = rptr[block_row];
        const int ecount = rptr[rend] - ebeg;
        __syncthreads();  // W-staging (first iter) / prev Phase B done
        for (int i = tid; i < ecount; i += 512) cp_s[i] = cpack[ebeg + i];
        __syncthreads();

        const int row0 = group;
        const int row1 = group + 32;
        const int node0 = block_row + row0;
        const int node1 = block_row + row1;
        float acc0[8], acc1[8];
#pragma unroll
        for (int i = 0; i < 8; ++i) { acc0[i] = bv[i]; acc1[i] = bv[i]; }
        int j0 = 0, e0 = 0, j1 = 0, e1 = 0;
        if (node0 < N) { j0 = rptr[node0] - ebeg; e0 = rptr[node0 + 1] - ebeg; }
        if (node1 < N) { j1 = rptr[node1] - ebeg; e1 = rptr[node1 + 1] - ebeg; }

        // ---- dual-row interleaved main loop (16 outstanding gathers)
        while (j0 + 8 <= e0 && j1 + 8 <= e1) {
            unsigned int p0[8], p1[8];
            uint4 s0[8], s1[8];
#pragma unroll
            for (int u = 0; u < 8; ++u) { p0[u] = cp_s[j0 + u]; p1[u] = cp_s[j1 + u]; }
#pragma unroll
            for (int u = 0; u < 8; ++u)
                s0[u] = *reinterpret_cast<const uint4*>(
                    S + (size_t)(p0[u] & 0xFFFF) * 128 + f8 * 8);
#pragma unroll
            for (int u = 0; u < 8; ++u)
                s1[u] = *reinterpret_cast<const uint4*>(
                    S + (size_t)(p1[u] & 0xFFFF) * 128 + f8 * 8);
#pragma unroll
            for (int u = 0; u < 8; ++u) {
                const float v = bf16_to_f32((unsigned short)(p0[u] >> 16));
                const unsigned short* sp =
                    reinterpret_cast<const unsigned short*>(&s0[u]);
#pragma unroll
                for (int i = 0; i < 8; ++i)
                    acc0[i] = fmaf(v, bf16_to_f32(sp[i]), acc0[i]);
            }
#pragma unroll
            for (int u = 0; u < 8; ++u) {
                const float v = bf16_to_f32((unsigned short)(p1[u] >> 16));
                const unsigned short* sp =
                    reinterpret_cast<const unsigned short*>(&s1[u]);
#pragma unroll
                for (int i = 0; i < 8; ++i)
                    acc1[i] = fmaf(v, bf16_to_f32(sp[i]), acc1[i]);
            }
            j0 += 8;
            j1 += 8;
        }
        // ---- tails (tiered 8/4/2/1 each)
        drain_row(S, cp_s, j0, e0, f8, acc0);
        drain_row(S, cp_s, j1, e1, f8, acc1);

        uint4 o0, o1;
        o0.x = (unsigned int)f32_to_bf16(fmaxf(acc0[0], 0.f)) |
               ((unsigned int)f32_to_bf16(fmaxf(acc0[1], 0.f)) << 16);
        o0.y = (unsigned int)f32_to_bf16(fmaxf(acc0[2], 0.f)) |
               ((unsigned int)f32_to_bf16(fmaxf(acc0[3], 0.f)) << 16);
        o0.z = (unsigned int)f32_to_bf16(fmaxf(acc0[4], 0.f)) |
               ((unsigned int)f32_to_bf16(fmaxf(acc0[5], 0.f)) << 16);
        o0.w = (unsigned int)f32_to_bf16(fmaxf(acc0[6], 0.f)) |
               ((unsigned int)f32_to_bf16(fmaxf(acc0[7], 0.f)) << 16);
        o1.x = (unsigned int)f32_to_bf16(fmaxf(acc1[0], 0.f)) |
               ((unsigned int)f32_to_bf16(fmaxf(acc1[1], 0.f)) << 16);
        o1.y = (unsigned int)f32_to_bf16(fmaxf(acc1[2], 0.f)) |
               ((unsigned int)f32_to_bf16(fmaxf(acc1[3], 0.f)) << 16);
        o1.z = (unsigned int)f32_to_bf16(fmaxf(acc1[4], 0.f)) |
               ((unsigned int)f32_to_bf16(fmaxf(acc1[5], 0.f)) << 16);
        o1.w = (unsigned int)f32_to_bf16(fmaxf(acc1[6], 0.f)) |
               ((unsigned int)f32_to_bf16(fmaxf(acc1[7], 0.f)) << 16);
        *reinterpret_cast<uint4*>(Xs + row0 * KP + f8 * 8) = o0;
        *reinterpret_cast<uint4*>(Xs + row1 * KP + f8 * 8) = o1;

        __syncthreads();
        mfma_phase512<NOUT>(Xs, Ws, Yb, block_row, N);
    }
}

// ---------------------------------------------------------------------------
// Final aggregation: bf16 source [N,64], + bias, no activation, fp32 out.
// 8 lanes/node; block's 32-node cpack slice staged in LDS (cap 1536 = +45s).
// ---------------------------------------------------------------------------
__global__ void aggregate_bf16_64(const unsigned short* __restrict__ S,
                                  const int* __restrict__ rptr,
                                  const unsigned int* __restrict__ cpack,
                                  const float* __restrict__ bias,
                                  float* __restrict__ out, int N) {
    __shared__ unsigned int cp_s[1536];
    const int t = threadIdx.x;
    const int nfirst = blockIdx.x * 32;
    const int node = nfirst + (t >> 3);
    const int f8 = t & 7;
    const int nlast1 = (nfirst + 32 < N) ? nfirst + 32 : N;
    int ebeg = 0, ecount = 0;
    if (nfirst < N) {
        ebeg = rptr[nfirst];
        ecount = rptr[nlast1] - ebeg;
    }
    for (int i = t; i < ecount; i += 256) cp_s[i] = cpack[ebeg + i];
    __syncthreads();
    if (node >= N) return;  // after the only barrier — safe
    int j = rptr[node] - ebeg;
    const int end = rptr[node + 1] - ebeg;
    float acc[8];
#pragma unroll
    for (int i = 0; i < 8; ++i) acc[i] = bias[f8 * 8 + i];
    for (; j + 8 <= end; j += 8) {
        unsigned int p[8];
        uint4 s[8];
#pragma unroll
        for (int u = 0; u < 8; ++u) p[u] = cp_s[j + u];
#pragma unroll
        for (int u = 0; u < 8; ++u)
            s[u] = *reinterpret_cast<const uint4*>(S + (size_t)(p[u] & 0xFFFF) * 64 + f8 * 8);
#pragma unroll
        for (int u = 0; u < 8; ++u) {
            const float v = bf16_to_f32((unsigned short)(p[u] >> 16));
            const unsigned short* sp = reinterpret_cast<const unsigned short*>(&s[u]);
#pragma unroll
            for (int i = 0; i < 8; ++i) acc[i] = fmaf(v, bf16_to_f32(sp[i]), acc[i]);
        }
    }
    if (j + 4 <= end) {
        unsigned int p[4];
        uint4 s[4];
#pragma unroll
        for (int u = 0; u < 4; ++u) p[u] = cp_s[j + u];
#pragma unroll
        for (int u = 0; u < 4; ++u)
            s[u] = *reinterpret_cast<const uint4*>(S + (size_t)(p[u] & 0xFFFF) * 64 + f8 * 8);
#pragma unroll
        for (int u = 0; u < 4; ++u) {
            const float v = bf16_to_f32((unsigned short)(p[u] >> 16));
            const unsigned short* sp = reinterpret_cast<const unsigned short*>(&s[u]);
#pragma unroll
            for (int i = 0; i < 8; ++i) acc[i] = fmaf(v, bf16_to_f32(sp[i]), acc[i]);
        }
        j += 4;
    }
    if (j + 2 <= end) {
        unsigned int p[2];
        uint4 s[2];
#pragma unroll
        for (int u = 0; u < 2; ++u) p[u] = cp_s[j + u];
#pragma unroll
        for (int u = 0; u < 2; ++u)
            s[u] = *reinterpret_cast<const uint4*>(S + (size_t)(p[u] & 0xFFFF) * 64 + f8 * 8);
#pragma unroll
        for (int u = 0; u < 2; ++u) {
            const float v = bf16_to_f32((unsigned short)(p[u] >> 16));
            const unsigned short* sp = reinterpret_cast<const unsigned short*>(&s[u]);
#pragma unroll
            for (int i = 0; i < 8; ++i) acc[i] = fmaf(v, bf16_to_f32(sp[i]), acc[i]);
        }
        j += 2;
    }
    if (j < end) {
        unsigned int p = cp_s[j];
        uint4 s = *reinterpret_cast<const uint4*>(S + (size_t)(p & 0xFFFF) * 64 + f8 * 8);
        const float v = bf16_to_f32((unsigned short)(p >> 16));
        const unsigned short* sp = reinterpret_cast<const unsigned short*>(&s);
#pragma unroll
        for (int i = 0; i < 8; ++i) acc[i] = fmaf(v, bf16_to_f32(sp[i]), acc[i]);
    }
    float4 o0 = {acc[0], acc[1], acc[2], acc[3]};
    float4 o1 = {acc[4], acc[5], acc[6], acc[7]};
    float* op = out + (size_t)node * 64 + f8 * 8;
    *reinterpret_cast<float4*>(op) = o0;
    *reinterpret_cast<float4*>(op + 4) = o1;
}

extern "C" void kernel_launch(void* const* d_in, const int* in_sizes, int n_in,
                              void* d_out, int out_size, void* d_ws, size_t ws_size,
                              hipStream_t stream) {
    const float* x    = (const float*)d_in[0];
    const int*   erow = (const int*)d_in[1];
    const int*   ecol = (const int*)d_in[2];
    const float* eval = (const float*)d_in[3];
    const float* W1   = (const float*)d_in[4];
    const float* b1   = (const float*)d_in[5];
    const float* W2   = (const float*)d_in[6];
    const float* b2   = (const float*)d_in[7];
    const float* W3   = (const float*)d_in[8];
    const float* b3   = (const float*)d_in[9];
    float* out = (float*)d_out;

    const size_t nf = (size_t)N_NODES * 128;
    unsigned short* SA   = (unsigned short*)d_ws;            // support A (A1, A3)
    unsigned short* SB   = SA + nf;                          // support B (A2)
    unsigned int*  rank8 = (unsigned int*)(SB + nf);         // N_EDGES/4 uints (u8 ranks)
    unsigned int*  bhist = rank8 + N_EDGES / 4;              // HB * HWORDS uints
    int*   bbase  = (int*)(bhist + (size_t)HB * HWORDS);     // HB * N_NODES
    int*   rptr   = bbase + (size_t)HB * N_NODES;            // N_NODES + 1
    unsigned int* cpack = (unsigned int*)(rptr + N_NODES + 1);  // N_EDGES
    int*   pref   = (int*)(cpack + N_EDGES);                 // N_NODES
    int*   btot   = pref + N_NODES;                          // SCAN_BLOCKS

    const int blk = 256;
    const int ntiles_g = (N_NODES + 63) / 64;  // 782
    const int agg_grid = (int)(((long long)N_NODES * 8 + blk - 1) / blk);

    // ---- 1. mega1: LDS chunk-histograms + rank (blocks 0..63) overlapped
    //         with layer-1 GEMM (blocks 64..767, grid-stride)
    mega1<<<HB + GEMM1_BLOCKS, blk, 0, stream>>>(
        x, W1, SA, N_NODES, ntiles_g, erow, rank8, bhist);

    // ---- 2. wide spin-free scan: deg+local prefix, then rptr+bbase
    scan1<<<SCAN_BLOCKS, blk, 0, stream>>>(bhist, pref, btot, N_NODES);
    scan2<<<SCAN_BLOCKS, blk, 0, stream>>>(bhist, pref, btot, rptr, bbase,
                                           N_NODES, SCAN_BLOCKS);

    // ---- 3. atomic-free CSR fill (full-device parallel)
    fill_csr<<<FILL_BLOCKS, blk, 0, stream>>>(erow, ecol, eval, bbase, rank8, cpack);

    // ---- 4. Layer 2: fused agg(A1)+ReLU+b1 -> GEMM W2 -> A2
    gemm_fused_agg<128><<<FUSED_BLOCKS, 512, 0, stream>>>(
        SA, rptr, cpack, b1, W2, SB, N_NODES, ntiles_g);

    // ---- 5. Layer 3: fused agg(A2)+ReLU+b2 -> GEMM W3 -> A3 (64-wide)
    gemm_fused_agg<64><<<FUSED_BLOCKS, 512, 0, stream>>>(
        SB, rptr, cpack, b2, W3, SA, N_NODES, ntiles_g);

    // ---- 6. Final aggregation: A3 + b3 -> out (fp32)
    aggregate_bf16_64<<<agg_grid, blk, 0, stream>>>(SA, rptr, cpack, b3, out, N_NODES);
}

// Round 13
// 217.522 us; speedup vs baseline: 1.0333x; 1.0309x over previous
//
#include <hip/hip_runtime.h>

#define N_NODES 50000
#define N_EDGES 800000
#define GEMM1_BLOCKS 704   // layer-1 gemm blocks; 64 CSR + 704 = 768 = 3/CU exact
#define FUSED_BLOCKS 512   // fused agg+gemm: 512-thr blocks, 2/CU (empirical best)
#define FILL_BLOCKS ((N_EDGES + 255) / 256)  // 3125
#define SCAN_BLOCKS ((N_NODES + 255) / 256)  // 196 (wide, spin-free scan)

// CSR build: per-chunk LDS histograms, u8-packed (NO global atomics — the
// memory-side atomic unit ceilings at ~7.6 ops/cycle device-wide, rounds 0-2).
// FINAL lessons ledger (12 rounds):
//  r4/r9:  spins co-resident with real work are catastrophic; r6: in-kernel
//          phases cap at kernel grid width => CSR chain stays as separate
//          dispatches; boundaries ARE the cheap barrier.
//  r7/r10: tail-balancing (dynamic grab, one-block-per-tile) is neutral.
//  r8:     cpack LDS staging in gather kernels is a win (BEST = 220.1us).
//  r11:    25-spinner scan + cum8 + vectorized fill: slightly negative.
//  r12:    dual-row gather interleave: neutral-negative (compiler already
//          pipelines across batches — addresses come from LDS, not FMAs).
//  => ~220us is the serial-dependency floor of this 7-dispatch pipeline;
//     every kernel is latency-bound (<10% of all pipes), with true data
//     dependencies at each boundary. This file = r8 verbatim.
#define HB 64                    // histogram chunks/blocks
#define EPB (N_EDGES / HB)       // 12500 edges per chunk (exact)
#define HGROUPS (EPB / 4)        // 3125 int4 groups per chunk
#define HWORDS (N_NODES / 4)     // 12500 uints (4 x u8 counts each) = 50 KB

static_assert(N_NODES < 65536, "col must fit in 16 bits for packed CSR");
static_assert(N_EDGES % (4 * HB) == 0, "chunking must be exact");

typedef __attribute__((ext_vector_type(4))) float f32x4;
typedef __attribute__((ext_vector_type(8))) short bf16x8;

__device__ inline unsigned short f32_to_bf16(float f) {
    unsigned int u = __builtin_bit_cast(unsigned int, f);
    u += 0x7FFF + ((u >> 16) & 1);  // RNE
    return (unsigned short)(u >> 16);
}
__device__ inline float bf16_to_f32(unsigned short h) {
    unsigned int u = ((unsigned int)h) << 16;
    return __builtin_bit_cast(float, u);
}

// ---------------------------------------------------------------------------
// MFMA phase, 256-thread variant (4 waves; wave w: rows w*16..+16, all tiles).
// Fragment layouts [measured m89/m91/m120].
// ---------------------------------------------------------------------------
template <int NOUT>
__device__ __forceinline__ void mfma_phase(const unsigned short* Xs,
                                           const unsigned short* Ws,
                                           unsigned short* __restrict__ Yb,
                                           int block_row, int N) {
    constexpr int KP = 128 + 8;
    constexpr int NT = NOUT / 16;
    const int tid = threadIdx.x;
    const int wave = tid >> 6;
    const int lane = tid & 63;
    const int m = lane & 15;
    const int quad = lane >> 4;
    const int rowbase = wave * 16;

    f32x4 acc[NT];
#pragma unroll
    for (int t = 0; t < NT; ++t) acc[t] = (f32x4){0.f, 0.f, 0.f, 0.f};

#pragma unroll
    for (int kt = 0; kt < 4; ++kt) {
        bf16x8 a = *reinterpret_cast<const bf16x8*>(
            Xs + (rowbase + m) * KP + kt * 32 + quad * 8);
#pragma unroll
        for (int t = 0; t < NT; ++t) {
            bf16x8 b = *reinterpret_cast<const bf16x8*>(
                Ws + (t * 16 + m) * KP + kt * 32 + quad * 8);
            acc[t] = __builtin_amdgcn_mfma_f32_16x16x32_bf16(a, b, acc[t], 0, 0, 0);
        }
    }

#pragma unroll
    for (int t = 0; t < NT; ++t) {
#pragma unroll
        for (int r = 0; r < 4; ++r) {
            int grow = block_row + rowbase + quad * 4 + r;
            if (grow < N)
                Yb[(size_t)grow * NOUT + t * 16 + m] = f32_to_bf16(acc[t][r]);
        }
    }
}

// ---------------------------------------------------------------------------
// Mega-dispatch 1: blocks 0..HB-1 build per-chunk LDS u8 histograms (rank8 +
// bhist, all LDS atomics); blocks HB.. run the layer-1 GEMM (W1 transposed
// from fp32 into LDS per-block). One 52 KB LDS union; 3 blocks/CU.
// ---------------------------------------------------------------------------
__global__ __launch_bounds__(256) void mega1(
    const float* __restrict__ x, const float* __restrict__ W1,
    unsigned short* __restrict__ Yb, int N, int ntiles_g,
    const int* __restrict__ erow, unsigned int* __restrict__ rank8,
    unsigned int* __restrict__ bhist) {
    constexpr int KP = 128 + 8;
    __shared__ __align__(16) unsigned char smem[52224];
    const int tid = threadIdx.x;

    if (blockIdx.x < HB) {
        const int b = blockIdx.x;
        unsigned int* h = reinterpret_cast<unsigned int*>(smem);  // HWORDS
        int4* h4 = reinterpret_cast<int4*>(h);
        for (int i = tid; i < HWORDS / 4; i += 256) {
            int4 z = {0, 0, 0, 0};
            h4[i] = z;
        }
        __syncthreads();
        const int4* eg = reinterpret_cast<const int4*>(erow) + (size_t)b * HGROUPS;
        unsigned int* rg = rank8 + (size_t)b * HGROUPS;
        for (int g = tid; g < HGROUPS; g += 256) {
            int4 er = eg[g];
            unsigned int rk;
            int sh;
            unsigned int o;
            sh = (er.x & 3) << 3;
            o = atomicAdd(&h[er.x >> 2], 1u << sh);
            rk = (o >> sh) & 0xFFu;
            sh = (er.y & 3) << 3;
            o = atomicAdd(&h[er.y >> 2], 1u << sh);
            rk |= ((o >> sh) & 0xFFu) << 8;
            sh = (er.z & 3) << 3;
            o = atomicAdd(&h[er.z >> 2], 1u << sh);
            rk |= ((o >> sh) & 0xFFu) << 16;
            sh = (er.w & 3) << 3;
            o = atomicAdd(&h[er.w >> 2], 1u << sh);
            rk |= ((o >> sh) & 0xFFu) << 24;
            rg[g] = rk;
        }
        __syncthreads();
        int4* dst = reinterpret_cast<int4*>(bhist + (size_t)b * HWORDS);
        for (int i = tid; i < HWORDS / 4; i += 256) dst[i] = h4[i];
        return;
    }

    // ---- GEMM part (grid-stride)
    const int gb = blockIdx.x - HB;
    unsigned short* Xs = reinterpret_cast<unsigned short*>(smem);   // 64*KP
    unsigned short* Ws = reinterpret_cast<unsigned short*>(smem) + 64 * KP;

    for (int idx = tid; idx < 128 * 128; idx += 256) {
        int k = idx >> 7, m = idx & 127;
        Ws[m * KP + k] = f32_to_bf16(W1[idx]);
    }

    for (int tile = gb; tile < ntiles_g; tile += GEMM1_BLOCKS) {
        const int block_row = tile * 64;
        for (int idx = tid; idx < 64 * 16; idx += 256) {
            int r = idx >> 4, ch = idx & 15;
            int gr = block_row + r;
            if (gr >= N) gr = N - 1;
            const float4* xp =
                reinterpret_cast<const float4*>(x + (size_t)gr * 128 + ch * 8);
            float4 a = xp[0], b2 = xp[1];
            uint4 o;
            o.x = (unsigned int)f32_to_bf16(a.x) | ((unsigned int)f32_to_bf16(a.y) << 16);
            o.y = (unsigned int)f32_to_bf16(a.z) | ((unsigned int)f32_to_bf16(a.w) << 16);
            o.z = (unsigned int)f32_to_bf16(b2.x) | ((unsigned int)f32_to_bf16(b2.y) << 16);
            o.w = (unsigned int)f32_to_bf16(b2.z) | ((unsigned int)f32_to_bf16(b2.w) << 16);
            *reinterpret_cast<uint4*>(Xs + r * KP + ch * 8) = o;
        }
        __syncthreads();
        mfma_phase<128>(Xs, Ws, Yb, block_row, N);
        __syncthreads();
    }
}

// ---------------------------------------------------------------------------
// Wide spin-free scan, part 1 (196 blocks, 256 thr, one node/thread):
// deg = sum of 64 u8 chunk hists; block-local exclusive prefix -> pref[];
// block total -> btot[b].
// ---------------------------------------------------------------------------
__global__ void scan1(const unsigned int* __restrict__ bhist,
                      int* __restrict__ pref, int* __restrict__ btot, int n) {
    __shared__ int sums[256];
    const int t = threadIdx.x;
    const int b = blockIdx.x;
    const int node = b * 256 + t;
    const unsigned char* bh8 = reinterpret_cast<const unsigned char*>(bhist);
    int deg = 0;
    if (node < n) {
        for (int c = 0; c < HB; ++c) deg += bh8[(size_t)c * N_NODES + node];
    }
    sums[t] = deg;
    __syncthreads();
    for (int off = 1; off < 256; off <<= 1) {
        int x = (t >= off) ? sums[t - off] : 0;
        __syncthreads();
        sums[t] += x;
        __syncthreads();
    }
    if (node < n) pref[node] = sums[t] - deg;
    if (t == 255) btot[b] = sums[255];
}

// ---------------------------------------------------------------------------
// Wide spin-free scan, part 2 (196 blocks): global offset from btot,
// rptr[node] = off + pref; bbase[c][node] = rptr + chunk-prefix (full-width
// 12.8 MB write).
// ---------------------------------------------------------------------------
__global__ void scan2(const unsigned int* __restrict__ bhist,
                      const int* __restrict__ pref, const int* __restrict__ btot,
                      int* __restrict__ rptr, int* __restrict__ bbase,
                      int n, int nblocks) {
    __shared__ int off_s, tot_s;
    const int t = threadIdx.x;
    const int b = blockIdx.x;
    const int node = b * 256 + t;
    if (t == 0) {
        int off = 0, tot = 0;
        for (int i = 0; i < nblocks; ++i) {
            int v = btot[i];
            if (i < b) off += v;
            tot += v;
        }
        off_s = off;
        tot_s = tot;
    }
    __syncthreads();
    if (node < n) {
        int run = off_s + pref[node];
        rptr[node] = run;
        const unsigned char* bh8 = reinterpret_cast<const unsigned char*>(bhist);
        for (int c = 0; c < HB; ++c) {
            bbase[(size_t)c * N_NODES + node] = run;
            run += bh8[(size_t)c * N_NODES + node];
        }
    }
    if (b == 0 && t == 0) rptr[n] = tot_s;
}

// ---------------------------------------------------------------------------
// Atomic-free CSR fill: slot = bbase[chunk(e)][row] + rank8[e]; 4B store.
// 3125 blocks: one edge per thread, full-device MLP.
// ---------------------------------------------------------------------------
__global__ void fill_csr(const int* __restrict__ erow, const int* __restrict__ ecol,
                         const float* __restrict__ eval, const int* __restrict__ bbase,
                         const unsigned int* __restrict__ rank8,
                         unsigned int* __restrict__ cpack) {
    int e = blockIdx.x * blockDim.x + threadIdx.x;
    if (e >= N_EDGES) return;
    const unsigned char* r8 = reinterpret_cast<const unsigned char*>(rank8);
    int slot = bbase[(size_t)(e / EPB) * N_NODES + erow[e]] + r8[e];
    unsigned int p = (unsigned int)(ecol[e] & 0xFFFF) |
                     ((unsigned int)f32_to_bf16(eval[e]) << 16);
    cpack[slot] = p;
}

// ---------------------------------------------------------------------------
// MFMA phase, 512-thread variant (8 waves; wave w: rows (w&3)*16..+16,
// tile-columns (w>>2)*NT/2..+NT/2).
// ---------------------------------------------------------------------------
template <int NOUT>
__device__ __forceinline__ void mfma_phase512(const unsigned short* Xs,
                                              const unsigned short* Ws,
                                              unsigned short* __restrict__ Yb,
                                              int block_row, int N) {
    constexpr int KP = 128 + 8;
    constexpr int NT = NOUT / 16;
    constexpr int NTH = NT / 2;
    const int tid = threadIdx.x;
    const int wave = tid >> 6;
    const int lane = tid & 63;
    const int m = lane & 15;
    const int quad = lane >> 4;
    const int rowbase = (wave & 3) * 16;
    const int tbase = (wave >> 2) * NTH;

    f32x4 acc[NTH];
#pragma unroll
    for (int t = 0; t < NTH; ++t) acc[t] = (f32x4){0.f, 0.f, 0.f, 0.f};

#pragma unroll
    for (int kt = 0; kt < 4; ++kt) {
        bf16x8 a = *reinterpret_cast<const bf16x8*>(
            Xs + (rowbase + m) * KP + kt * 32 + quad * 8);
#pragma unroll
        for (int t = 0; t < NTH; ++t) {
            bf16x8 b = *reinterpret_cast<const bf16x8*>(
                Ws + ((tbase + t) * 16 + m) * KP + kt * 32 + quad * 8);
            acc[t] = __builtin_amdgcn_mfma_f32_16x16x32_bf16(a, b, acc[t], 0, 0, 0);
        }
    }

#pragma unroll
    for (int t = 0; t < NTH; ++t) {
#pragma unroll
        for (int r = 0; r < 4; ++r) {
            int grow = block_row + rowbase + quad * 4 + r;
            if (grow < N)
                Yb[(size_t)grow * NOUT + (tbase + t) * 16 + m] = f32_to_bf16(acc[t][r]);
        }
    }
}

// ---------------------------------------------------------------------------
// Fused aggregation + GEMM (layers 2,3), 512-thread blocks, 2 blocks/CU,
// r5/r8 static row assignment. Tile's contiguous cpack slice staged in LDS
// (mean 1024, cap 2048 = +32 sigma). Phase A: 32 groups x 16 lanes
// gather-aggregate 64 rows (+bias, ReLU, pack bf16 into Xs).
// Phase B: mfma_phase512.
// ---------------------------------------------------------------------------
template <int NOUT>
__global__ __launch_bounds__(512, 4) void gemm_fused_agg(
    const unsigned short* __restrict__ S,
    const int* __restrict__ rptr, const unsigned int* __restrict__ cpack,
    const float* __restrict__ bias,
    const float* __restrict__ W,
    unsigned short* __restrict__ Yb,
    int N, int ntiles) {
    constexpr int KP = 128 + 8;
    __shared__ unsigned short Xs[64 * KP];
    __shared__ unsigned short Ws[NOUT * KP];
    __shared__ unsigned int cp_s[2048];
    const int tid = threadIdx.x;
    const int group = tid >> 4;   // 0..31
    const int f8 = tid & 15;

    for (int idx = tid; idx < 128 * NOUT; idx += 512) {
        int k = idx / NOUT, m = idx % NOUT;
        Ws[m * KP + k] = f32_to_bf16(W[idx]);
    }

    float bv[8];
#pragma unroll
    for (int i = 0; i < 8; ++i) bv[i] = bias[f8 * 8 + i];

    for (int tile = blockIdx.x; tile < ntiles; tile += gridDim.x) {
        const int block_row = tile * 64;
        const int rend = (block_row + 64 < N) ? block_row + 64 : N;
        const int ebeg = rptr[block_row];
        const int ecount = rptr[rend] - ebeg;
        __syncthreads();  // W-staging (first iter) / prev Phase B done
        for (int i = tid; i < ecount; i += 512) cp_s[i] = cpack[ebeg + i];
        __syncthreads();
#pragma unroll
        for (int r4 = 0; r4 < 2; ++r4) {
            const int row = r4 * 32 + group;
            const int node = block_row + row;
            float acc[8];
#pragma unroll
            for (int i = 0; i < 8; ++i) acc[i] = bv[i];
            if (node < N) {
                const int beg = rptr[node] - ebeg;
                const int end = rptr[node + 1] - ebeg;
                int j = beg;
                for (; j + 8 <= end; j += 8) {
                    unsigned int p[8];
                    uint4 s[8];
#pragma unroll
                    for (int u = 0; u < 8; ++u) p[u] = cp_s[j + u];
#pragma unroll
                    for (int u = 0; u < 8; ++u)
                        s[u] = *reinterpret_cast<const uint4*>(
                            S + (size_t)(p[u] & 0xFFFF) * 128 + f8 * 8);
#pragma unroll
                    for (int u = 0; u < 8; ++u) {
                        const float v = bf16_to_f32((unsigned short)(p[u] >> 16));
                        const unsigned short* sp =
                            reinterpret_cast<const unsigned short*>(&s[u]);
#pragma unroll
                        for (int i = 0; i < 8; ++i)
                            acc[i] = fmaf(v, bf16_to_f32(sp[i]), acc[i]);
                    }
                }
                if (j + 4 <= end) {
                    unsigned int p[4];
                    uint4 s[4];
#pragma unroll
                    for (int u = 0; u < 4; ++u) p[u] = cp_s[j + u];
#pragma unroll
                    for (int u = 0; u < 4; ++u)
                        s[u] = *reinterpret_cast<const uint4*>(
                            S + (size_t)(p[u] & 0xFFFF) * 128 + f8 * 8);
#pragma unroll
                    for (int u = 0; u < 4; ++u) {
                        const float v = bf16_to_f32((unsigned short)(p[u] >> 16));
                        const unsigned short* sp =
                            reinterpret_cast<const unsigned short*>(&s[u]);
#pragma unroll
                        for (int i = 0; i < 8; ++i)
                            acc[i] = fmaf(v, bf16_to_f32(sp[i]), acc[i]);
                    }
                    j += 4;
                }
                if (j + 2 <= end) {
                    unsigned int p[2];
                    uint4 s[2];
#pragma unroll
                    for (int u = 0; u < 2; ++u) p[u] = cp_s[j + u];
#pragma unroll
                    for (int u = 0; u < 2; ++u)
                        s[u] = *reinterpret_cast<const uint4*>(
                            S + (size_t)(p[u] & 0xFFFF) * 128 + f8 * 8);
#pragma unroll
                    for (int u = 0; u < 2; ++u) {
                        const float v = bf16_to_f32((unsigned short)(p[u] >> 16));
                        const unsigned short* sp =
                            reinterpret_cast<const unsigned short*>(&s[u]);
#pragma unroll
                        for (int i = 0; i < 8; ++i)
                            acc[i] = fmaf(v, bf16_to_f32(sp[i]), acc[i]);
                    }
                    j += 2;
                }
                if (j < end) {
                    unsigned int p = cp_s[j];
                    uint4 s = *reinterpret_cast<const uint4*>(
                        S + (size_t)(p & 0xFFFF) * 128 + f8 * 8);
                    const float v = bf16_to_f32((unsigned short)(p >> 16));
                    const unsigned short* sp =
                        reinterpret_cast<const unsigned short*>(&s);
#pragma unroll
                    for (int i = 0; i < 8; ++i)
                        acc[i] = fmaf(v, bf16_to_f32(sp[i]), acc[i]);
                }
            }
            uint4 o;
            o.x = (unsigned int)f32_to_bf16(fmaxf(acc[0], 0.f)) |
                  ((unsigned int)f32_to_bf16(fmaxf(acc[1], 0.f)) << 16);
            o.y = (unsigned int)f32_to_bf16(fmaxf(acc[2], 0.f)) |
                  ((unsigned int)f32_to_bf16(fmaxf(acc[3], 0.f)) << 16);
            o.z = (unsigned int)f32_to_bf16(fmaxf(acc[4], 0.f)) |
                  ((unsigned int)f32_to_bf16(fmaxf(acc[5], 0.f)) << 16);
            o.w = (unsigned int)f32_to_bf16(fmaxf(acc[6], 0.f)) |
                  ((unsigned int)f32_to_bf16(fmaxf(acc[7], 0.f)) << 16);
            *reinterpret_cast<uint4*>(Xs + row * KP + f8 * 8) = o;
        }
        __syncthreads();
        mfma_phase512<NOUT>(Xs, Ws, Yb, block_row, N);
    }
}

// ---------------------------------------------------------------------------
// Final aggregation: bf16 source [N,64], + bias, no activation, fp32 out.
// 8 lanes/node; block's 32-node cpack slice staged in LDS (cap 1536 = +45s).
// ---------------------------------------------------------------------------
__global__ void aggregate_bf16_64(const unsigned short* __restrict__ S,
                                  const int* __restrict__ rptr,
                                  const unsigned int* __restrict__ cpack,
                                  const float* __restrict__ bias,
                                  float* __restrict__ out, int N) {
    __shared__ unsigned int cp_s[1536];
    const int t = threadIdx.x;
    const int nfirst = blockIdx.x * 32;
    const int node = nfirst + (t >> 3);
    const int f8 = t & 7;
    const int nlast1 = (nfirst + 32 < N) ? nfirst + 32 : N;
    int ebeg = 0, ecount = 0;
    if (nfirst < N) {
        ebeg = rptr[nfirst];
        ecount = rptr[nlast1] - ebeg;
    }
    for (int i = t; i < ecount; i += 256) cp_s[i] = cpack[ebeg + i];
    __syncthreads();
    if (node >= N) return;  // after the only barrier — safe
    int j = rptr[node] - ebeg;
    const int end = rptr[node + 1] - ebeg;
    float acc[8];
#pragma unroll
    for (int i = 0; i < 8; ++i) acc[i] = bias[f8 * 8 + i];
    for (; j + 8 <= end; j += 8) {
        unsigned int p[8];
        uint4 s[8];
#pragma unroll
        for (int u = 0; u < 8; ++u) p[u] = cp_s[j + u];
#pragma unroll
        for (int u = 0; u < 8; ++u)
            s[u] = *reinterpret_cast<const uint4*>(S + (size_t)(p[u] & 0xFFFF) * 64 + f8 * 8);
#pragma unroll
        for (int u = 0; u < 8; ++u) {
            const float v = bf16_to_f32((unsigned short)(p[u] >> 16));
            const unsigned short* sp = reinterpret_cast<const unsigned short*>(&s[u]);
#pragma unroll
            for (int i = 0; i < 8; ++i) acc[i] = fmaf(v, bf16_to_f32(sp[i]), acc[i]);
        }
    }
    if (j + 4 <= end) {
        unsigned int p[4];
        uint4 s[4];
#pragma unroll
        for (int u = 0; u < 4; ++u) p[u] = cp_s[j + u];
#pragma unroll
        for (int u = 0; u < 4; ++u)
            s[u] = *reinterpret_cast<const uint4*>(S + (size_t)(p[u] & 0xFFFF) * 64 + f8 * 8);
#pragma unroll
        for (int u = 0; u < 4; ++u) {
            const float v = bf16_to_f32((unsigned short)(p[u] >> 16));
            const unsigned short* sp = reinterpret_cast<const unsigned short*>(&s[u]);
#pragma unroll
            for (int i = 0; i < 8; ++i) acc[i] = fmaf(v, bf16_to_f32(sp[i]), acc[i]);
        }
        j += 4;
    }
    if (j + 2 <= end) {
        unsigned int p[2];
        uint4 s[2];
#pragma unroll
        for (int u = 0; u < 2; ++u) p[u] = cp_s[j + u];
#pragma unroll
        for (int u = 0; u < 2; ++u)
            s[u] = *reinterpret_cast<const uint4*>(S + (size_t)(p[u] & 0xFFFF) * 64 + f8 * 8);
#pragma unroll
        for (int u = 0; u < 2; ++u) {
            const float v = bf16_to_f32((unsigned short)(p[u] >> 16));
            const unsigned short* sp = reinterpret_cast<const unsigned short*>(&s[u]);
#pragma unroll
            for (int i = 0; i < 8; ++i) acc[i] = fmaf(v, bf16_to_f32(sp[i]), acc[i]);
        }
        j += 2;
    }
    if (j < end) {
        unsigned int p = cp_s[j];
        uint4 s = *reinterpret_cast<const uint4*>(S + (size_t)(p & 0xFFFF) * 64 + f8 * 8);
        const float v = bf16_to_f32((unsigned short)(p >> 16));
        const unsigned short* sp = reinterpret_cast<const unsigned short*>(&s);
#pragma unroll
        for (int i = 0; i < 8; ++i) acc[i] = fmaf(v, bf16_to_f32(sp[i]), acc[i]);
    }
    float4 o0 = {acc[0], acc[1], acc[2], acc[3]};
    float4 o1 = {acc[4], acc[5], acc[6], acc[7]};
    float* op = out + (size_t)node * 64 + f8 * 8;
    *reinterpret_cast<float4*>(op) = o0;
    *reinterpret_cast<float4*>(op + 4) = o1;
}

extern "C" void kernel_launch(void* const* d_in, const int* in_sizes, int n_in,
                              void* d_out, int out_size, void* d_ws, size_t ws_size,
                              hipStream_t stream) {
    const float* x    = (const float*)d_in[0];
    const int*   erow = (const int*)d_in[1];
    const int*   ecol = (const int*)d_in[2];
    const float* eval = (const float*)d_in[3];
    const float* W1   = (const float*)d_in[4];
    const float* b1   = (const float*)d_in[5];
    const float* W2   = (const float*)d_in[6];
    const float* b2   = (const float*)d_in[7];
    const float* W3   = (const float*)d_in[8];
    const float* b3   = (const float*)d_in[9];
    float* out = (float*)d_out;

    const size_t nf = (size_t)N_NODES * 128;
    unsigned short* SA   = (unsigned short*)d_ws;            // support A (A1, A3)
    unsigned short* SB   = SA + nf;                          // support B (A2)
    unsigned int*  rank8 = (unsigned int*)(SB + nf);         // N_EDGES/4 uints (u8 ranks)
    unsigned int*  bhist = rank8 + N_EDGES / 4;              // HB * HWORDS uints
    int*   bbase  = (int*)(bhist + (size_t)HB * HWORDS);     // HB * N_NODES
    int*   rptr   = bbase + (size_t)HB * N_NODES;            // N_NODES + 1
    unsigned int* cpack = (unsigned int*)(rptr + N_NODES + 1);  // N_EDGES
    int*   pref   = (int*)(cpack + N_EDGES);                 // N_NODES
    int*   btot   = pref + N_NODES;                          // SCAN_BLOCKS

    const int blk = 256;
    const int ntiles_g = (N_NODES + 63) / 64;  // 782
    const int agg_grid = (int)(((long long)N_NODES * 8 + blk - 1) / blk);

    // ---- 1. mega1: LDS chunk-histograms + rank (blocks 0..63) overlapped
    //         with layer-1 GEMM (blocks 64..767, grid-stride)
    mega1<<<HB + GEMM1_BLOCKS, blk, 0, stream>>>(
        x, W1, SA, N_NODES, ntiles_g, erow, rank8, bhist);

    // ---- 2. wide spin-free scan: deg+local prefix, then rptr+bbase
    scan1<<<SCAN_BLOCKS, blk, 0, stream>>>(bhist, pref, btot, N_NODES);
    scan2<<<SCAN_BLOCKS, blk, 0, stream>>>(bhist, pref, btot, rptr, bbase,
                                           N_NODES, SCAN_BLOCKS);

    // ---- 3. atomic-free CSR fill (full-device parallel)
    fill_csr<<<FILL_BLOCKS, blk, 0, stream>>>(erow, ecol, eval, bbase, rank8, cpack);

    // ---- 4. Layer 2: fused agg(A1)+ReLU+b1 -> GEMM W2 -> A2
    gemm_fused_agg<128><<<FUSED_BLOCKS, 512, 0, stream>>>(
        SA, rptr, cpack, b1, W2, SB, N_NODES, ntiles_g);

    // ---- 5. Layer 3: fused agg(A2)+ReLU+b2 -> GEMM W3 -> A3 (64-wide)
    gemm_fused_agg<64><<<FUSED_BLOCKS, 512, 0, stream>>>(
        SB, rptr, cpack, b2, W3, SA, N_NODES, ntiles_g);

    // ---- 6. Final aggregation: A3 + b3 -> out (fp32)
    aggregate_bf16_64<<<agg_grid, blk, 0, stream>>>(SA, rptr, cpack, b3, out, N_NODES);
}